// Round 4
// baseline (448.270 us; speedup 1.0000x reference)
//
#include <hip/hip_runtime.h>

// Problem constants (C,H,W,hi,wi) = (32,32,32,32,32)
constexpr int NPIX  = 32 * 32 * 32;     // C*H*W pixels
constexpr int TILE  = 32 * 32;          // hi*wi elements per pixel
constexpr long NBIG = (long)NPIX * TILE;
constexpr int THREADS = 256;            // 4 waves -> 4 independent pixels/block
constexpr int PIX_PER_BLOCK = THREADS / 64;

// Native Clang vector type: accepted by __builtin_nontemporal_* (HIP's
// float4 struct is not).
typedef float v4f __attribute__((ext_vector_type(4)));

__global__ __launch_bounds__(THREADS)
void relu_conv_kernel(const float* __restrict__ lx_in,
                      const float* __restrict__ ux_in,
                      const float* __restrict__ lc_in,
                      const float* __restrict__ uc_in,
                      const float* __restrict__ x_min,
                      const float* __restrict__ x_max,
                      float* __restrict__ lx_out,
                      float* __restrict__ ux_out,
                      float* __restrict__ lc_out,
                      float* __restrict__ uc_out)
{
    const int lane = threadIdx.x & 63;
    const int wave = threadIdx.x >> 6;
    const int p = blockIdx.x * PIX_PER_BLOCK + wave;   // pixel index

    const long base = (long)p * TILE;

    // Wave-uniform scalar loads; issue early so they're ready at the epilogue.
    const float lc = lc_in[p];
    const float uc = uc_in[p];

    // Lane i covers tile offsets {lane*4 + j*256 : j=0..3}; each wave load is
    // 64 lanes x 16 B = 1 KiB contiguous. Loads are CACHED (L2/L3 can serve
    // the freshly-restored inputs); stores are nontemporal so the 268 MB
    // output stream doesn't evict the inputs from Infinity Cache.
    v4f lx[4], ux[4];
    float sl = 0.f, su = 0.f;
    #pragma unroll
    for (int j = 0; j < 4; ++j) {
        const int off = lane * 4 + j * 256;
        lx[j] = *reinterpret_cast<const v4f*>(lx_in + base + off);
        ux[j] = *reinterpret_cast<const v4f*>(ux_in + base + off);
        const v4f mn = *reinterpret_cast<const v4f*>(x_min + off);
        const v4f mx = *reinterpret_cast<const v4f*>(x_max + off);

        #pragma unroll
        for (int k = 0; k < 4; ++k) {
            const float a = lx[j][k];
            const float b = ux[j][k];
            const float ml = a > 0.f ? mn[k] : (a < 0.f ? mx[k] : 0.f);
            const float mu = b > 0.f ? mx[k] : (b < 0.f ? mn[k] : 0.f);
            sl += ml * a;
            su += mu * b;
        }
    }

    // Wave-wide butterfly reduction: all 64 lanes end with the full sums.
    #pragma unroll
    for (int m = 32; m > 0; m >>= 1) {
        sl += __shfl_xor(sl, m, 64);
        su += __shfl_xor(su, m, 64);
    }

    const float l = sl + lc;
    const float u = su + uc;

    const bool alive = (l >= 0.f);
    const bool cross = (l < 0.f) && (u > 0.f);
    float slope = cross ? (u / (u - l)) : 1.f;
    slope = fminf(fmaxf(slope, 0.f), 1.f);

    const float fl = alive ? 1.f : 0.f;
    const float fu = alive ? 1.f : (cross ? slope : 0.f);

    #pragma unroll
    for (int j = 0; j < 4; ++j) {
        const int off = lane * 4 + j * 256;
        v4f lo4 = lx[j] * fl;
        v4f uo4 = ux[j] * fu;
        __builtin_nontemporal_store(lo4,
            reinterpret_cast<v4f*>(lx_out + base + off));
        __builtin_nontemporal_store(uo4,
            reinterpret_cast<v4f*>(ux_out + base + off));
    }

    if (lane == 0) {
        lc_out[p] = alive ? lc : 0.f;
        uc_out[p] = alive ? uc : (cross ? (slope * uc - slope * l) : 0.f);
    }
}

extern "C" void kernel_launch(void* const* d_in, const int* in_sizes, int n_in,
                              void* d_out, int out_size, void* d_ws, size_t ws_size,
                              hipStream_t stream) {
    const float* lx_in = (const float*)d_in[0];
    const float* ux_in = (const float*)d_in[1];
    const float* lc_in = (const float*)d_in[2];
    const float* uc_in = (const float*)d_in[3];
    const float* x_min = (const float*)d_in[4];
    const float* x_max = (const float*)d_in[5];

    float* out = (float*)d_out;
    float* lx_out = out;                         // NBIG
    float* ux_out = out + NBIG;                  // NBIG
    float* lc_out = out + 2 * NBIG;              // NPIX
    float* uc_out = lc_out + NPIX;               // NPIX

    relu_conv_kernel<<<dim3(NPIX / PIX_PER_BLOCK), dim3(THREADS), 0, stream>>>(
        lx_in, ux_in, lc_in, uc_in, x_min, x_max,
        lx_out, ux_out, lc_out, uc_out);
}